// Round 13
// baseline (538.495 us; speedup 1.0000x reference)
//
#include <hip/hip_runtime.h>

#define SCAN_B 1024

typedef __attribute__((ext_vector_type(8))) short bf16x8;
typedef __attribute__((ext_vector_type(4))) float f32x4;

#define MFMA16(a, b, c) __builtin_amdgcn_mfma_f32_16x16x32_bf16(a, b, c, 0, 0, 0)

// round-to-nearest-even fp32 -> bf16 (as ushort)
__device__ __forceinline__ unsigned short bf16rn(float f) {
    unsigned u = __float_as_uint(f);
    u += 0x7fffu + ((u >> 16) & 1u);
    return (unsigned short)(u >> 16);
}

// pack 8 floats into hi/lo bf16x8 (split: x = hi + lo, each bf16)
__device__ __forceinline__ void packhl(const float4 v0, const float4 v1,
                                       bf16x8* hi, bf16x8* lo)
{
    float e[8] = { v0.x, v0.y, v0.z, v0.w, v1.x, v1.y, v1.z, v1.w };
#pragma unroll
    for (int i = 0; i < 8; ++i) {
        unsigned short h = bf16rn(e[i]);
        (*hi)[i] = (short)h;
        float hf = __uint_as_float((unsigned)h << 16);
        (*lo)[i] = (short)bf16rn(e[i] - hf);
    }
}

// ---------------- CSR build ----------------
__global__ __launch_bounds__(256) void k_zero(int* __restrict__ cnt, int n) {
    int i = blockIdx.x * 256 + threadIdx.x;
    if (i < n) cnt[i] = 0;
}

__global__ __launch_bounds__(256) void k_hist(
    const int* __restrict__ dst_a, const int* __restrict__ dst_b,
    int* __restrict__ cnt, int n_a, int E)
{
    int i = blockIdx.x * 256 + threadIdx.x;
    if (i >= 2 * E) return;
    int idx = (i < E) ? dst_a[i] : (n_a + dst_b[i - E]);
    atomicAdd(&cnt[idx], 1);
}

__global__ __launch_bounds__(SCAN_B) void k_scan1(
    const int* __restrict__ cnt, int n, int* __restrict__ rowptr, int* __restrict__ bsum)
{
    __shared__ int tmp[SCAN_B];
    int i = blockIdx.x * SCAN_B + threadIdx.x;
    int v = (i < n) ? cnt[i] : 0;
    tmp[threadIdx.x] = v;
    __syncthreads();
    for (int off = 1; off < SCAN_B; off <<= 1) {
        int t = (threadIdx.x >= (unsigned)off) ? tmp[threadIdx.x - off] : 0;
        __syncthreads();
        tmp[threadIdx.x] += t;
        __syncthreads();
    }
    if (i < n) rowptr[i] = tmp[threadIdx.x] - v;   // exclusive
    if (threadIdx.x == SCAN_B - 1) bsum[blockIdx.x] = tmp[threadIdx.x];
}

__global__ __launch_bounds__(SCAN_B) void k_scan2(int* __restrict__ bsum, int nb) {
    __shared__ int tmp[SCAN_B];
    int i = threadIdx.x;
    int v = (i < nb) ? bsum[i] : 0;
    tmp[i] = v;
    __syncthreads();
    for (int off = 1; off < SCAN_B; off <<= 1) {
        int t = (i >= off) ? tmp[i - off] : 0;
        __syncthreads();
        tmp[i] += t;
        __syncthreads();
    }
    if (i < nb) bsum[i] = tmp[i] - v;              // exclusive
}

__global__ __launch_bounds__(256) void k_scan3(
    int* __restrict__ rowptr, int* __restrict__ cursor,
    const int* __restrict__ bsum, int n, int total)
{
    int i = blockIdx.x * 256 + threadIdx.x;
    if (i < n) {
        int r = rowptr[i] + bsum[i / SCAN_B];
        rowptr[i] = r;
        cursor[i] = r;
    }
    if (i == 0) rowptr[n] = total;
}

__global__ __launch_bounds__(256) void k_fill(
    const int* __restrict__ src_a, const int* __restrict__ dst_a,
    const int* __restrict__ src_b, const int* __restrict__ dst_b,
    int* __restrict__ cursor, int* __restrict__ sorted_src, int n_a, int E)
{
    int i = blockIdx.x * 256 + threadIdx.x;
    if (i >= 2 * E) return;
    int idx, s;
    if (i < E) { idx = dst_a[i];            s = src_a[i]; }
    else       { idx = n_a + dst_b[i - E];  s = src_b[i - E]; }
    int pos = atomicAdd(&cursor[idx], 1);
    sorted_src[pos] = s;
}

// ---------- W prep: transpose + bf16 hi/lo split -----------------------------
// WT*[n][k], n in [0,256): n<128 -> W0 col n, n>=128 -> W1 col n-128.
// WT[n][k] = bf16(W[k][n]); lo = bf16(W - hi).
__global__ __launch_bounds__(64) void k_wprep(
    const float* __restrict__ W0u, const float* __restrict__ W1u,
    const float* __restrict__ W0i, const float* __restrict__ W1i,
    unsigned short* __restrict__ WTuh, unsigned short* __restrict__ WTul,
    unsigned short* __restrict__ WTih, unsigned short* __restrict__ WTil)
{
    int b = blockIdx.x;              // 0..511
    int dir = b >> 8;
    int n = b & 255;
    const float* W = (n < 128) ? (dir ? W0i : W0u) : (dir ? W1i : W1u);
    unsigned short* Th = dir ? WTih : WTuh;
    unsigned short* Tl = dir ? WTil : WTul;
    int col = n & 127;
    for (int k = threadIdx.x; k < 128; k += 64) {
        float w = W[(size_t)k * 128 + col];
        unsigned short h = bf16rn(w);
        float hf = __uint_as_float((unsigned)h << 16);
        unsigned short l = bf16rn(w - hf);
        Th[(size_t)n * 128 + k] = h;
        Tl[(size_t)n * 128 + k] = l;
    }
}

// ---------- split-bf16 MFMA GEMM: Y0|Y1 [M,128|128] = X[M,128] @ (W0|W1) ----
// One wave per 32 rows x 256 cols. No LDS, no barriers. 3 MFMAs per frag-pair
// (hiHi + loHi + hiLo); lo*lo dropped (~2^-18 rel). A from global fp32,
// packed in-register; B from pre-split WT (bf16, k-major, L2-resident).
// Frag layouts (m89/m91/m92): A row=l&15, k=(l>>4)*8+j; B col=l&15, same k;
// D col=l&15, row=(l>>4)*4+reg.
__global__ __launch_bounds__(256) void gemm_mfma(
    const float* __restrict__ X0,
    const unsigned short* __restrict__ WT0h, const unsigned short* __restrict__ WT0l,
    const float* __restrict__ B00, const float* __restrict__ B01,
    float* __restrict__ Y00, float* __restrict__ Y01, int M0, int nw0,
    const float* __restrict__ X1,
    const unsigned short* __restrict__ WT1h, const unsigned short* __restrict__ WT1l,
    const float* __restrict__ B10, const float* __restrict__ B11,
    float* __restrict__ Y10, float* __restrict__ Y11, int M1, int nw_all)
{
    int gw = (blockIdx.x * 256 + threadIdx.x) >> 6;
    if (gw >= nw_all) return;
    const int lane = threadIdx.x & 63;

    const float* X; const unsigned short *Wh, *Wl; const float *B0, *B1;
    float *Y0, *Y1; int M, strip;
    if (gw < nw0) { X = X0; Wh = WT0h; Wl = WT0l; B0 = B00; B1 = B01;
                    Y0 = Y00; Y1 = Y01; M = M0; strip = gw; }
    else          { X = X1; Wh = WT1h; Wl = WT1l; B0 = B10; B1 = B11;
                    Y0 = Y10; Y1 = Y11; M = M1; strip = gw - nw0; }

    const int r0   = strip * 32;
    const int cw   = lane & 15;          // frag col / A row offset
    const int g    = lane >> 4;          // k-group
    const int rA   = r0 + cw;            // A-frag0 source row
    const int rB   = rA + 16;            // A-frag1 source row
    const bool vA  = rA < M;
    const bool vB  = rB < M;
    const float* xpA = X + (size_t)rA * 128;
    const float* xpB = X + (size_t)rB * 128;
    const unsigned short* wph = Wh + (size_t)cw * 128;
    const unsigned short* wpl = Wl + (size_t)cw * 128;

    f32x4 acc0[16], acc1[16];
#pragma unroll
    for (int j = 0; j < 16; ++j) {
        acc0[j] = (f32x4){0.f, 0.f, 0.f, 0.f};
        acc1[j] = (f32x4){0.f, 0.f, 0.f, 0.f};
    }

    const float4 z4 = make_float4(0.f, 0.f, 0.f, 0.f);
#pragma unroll
    for (int kc = 0; kc < 128; kc += 32) {
        const int kb = kc + g * 8;
        float4 a0 = vA ? *(const float4*)(xpA + kb)     : z4;
        float4 a1 = vA ? *(const float4*)(xpA + kb + 4) : z4;
        float4 a2 = vB ? *(const float4*)(xpB + kb)     : z4;
        float4 a3 = vB ? *(const float4*)(xpB + kb + 4) : z4;
        bf16x8 ah0, al0, ah1, al1;
        packhl(a0, a1, &ah0, &al0);
        packhl(a2, a3, &ah1, &al1);
#pragma unroll
        for (int j = 0; j < 16; ++j) {
            const size_t off = (size_t)j * 16 * 128 + kb;
            bf16x8 bh = *(const bf16x8*)(wph + off);
            bf16x8 bl = *(const bf16x8*)(wpl + off);
            acc0[j] = MFMA16(ah0, bh, acc0[j]);
            acc0[j] = MFMA16(al0, bh, acc0[j]);
            acc0[j] = MFMA16(ah0, bl, acc0[j]);
            acc1[j] = MFMA16(ah1, bh, acc1[j]);
            acc1[j] = MFMA16(al1, bh, acc1[j]);
            acc1[j] = MFMA16(ah1, bl, acc1[j]);
        }
    }

    // store: D col = l&15, row = (l>>4)*4 + r. j<8 -> Y0, j>=8 -> Y1.
    const int rs = r0 + g * 4;
#pragma unroll
    for (int j = 0; j < 16; ++j) {
        float* Yt = (j < 8) ? Y0 : Y1;
        const float* Bt = (j < 8) ? B0 : B1;
        int cc = ((j & 7) * 16) + cw;
        float bv = Bt[cc];
#pragma unroll
        for (int r = 0; r < 4; ++r) {
            int R = rs + r;
            if (R < M)      Yt[(size_t)R * 128 + cc]        = acc0[j][r] + bv;
            if (R + 16 < M) Yt[(size_t)(R + 16) * 128 + cc] = acc1[j][r] + bv;
        }
    }
}

// ---------- fused GAT, both directions in one grid; one wave per dst node ---
// Lane covers ADJACENT channels (h*64+2j, +1) -> float2 gathers. No running
// max (|logit| <~ 8, fp32-safe; identical alpha).
__global__ __launch_bounds__(256) void k_gat2(
    const float* __restrict__ xl_a, const float* __restrict__ xr_a,
    const float* __restrict__ att_a, const float* __restrict__ bias_a,
    float* __restrict__ out_a,
    const float* __restrict__ xl_b, const float* __restrict__ xr_b,
    const float* __restrict__ att_b, const float* __restrict__ bias_b,
    float* __restrict__ out_b,
    const int* __restrict__ rowptr, const int* __restrict__ srcs,
    int n_a, int n_all)
{
    int wave = (blockIdx.x * 256 + threadIdx.x) >> 6;
    if (wave >= n_all) return;
    const int lane = threadIdx.x & 63;
    const int h = lane >> 5;
    const int j = lane & 31;
    const int ch = h * 64 + 2 * j;

    const float *xl, *xr, *att, *bias;
    float* out;
    int d;
    if (wave < n_a) { xl = xl_a; xr = xr_a; att = att_a; bias = bias_a; out = out_a; d = wave; }
    else            { xl = xl_b; xr = xr_b; att = att_b; bias = bias_b; out = out_b; d = wave - n_a; }

    const int base = rowptr[wave];
    const int end  = rowptr[wave + 1];
    if (base == end) {
        if (lane < 32) {
            float2 bv = *(const float2*)&bias[2 * j];
            *(float2*)&out[(size_t)d * 64 + 2 * j] = bv;
        }
        return;
    }

    const float2 xi = *(const float2*)&xr[(size_t)d * 128 + ch];
    const float2 at = *(const float2*)&att[ch];

    float den = 0.f, a0 = 0.f, a1 = 0.f;
    int k = base;
    for (; k + 1 < end; k += 2) {
        int s0 = srcs[k];
        int s1 = srcs[k + 1];
        float2 x0 = *(const float2*)&xl[(size_t)s0 * 128 + ch];
        float2 x1 = *(const float2*)&xl[(size_t)s1 * 128 + ch];
        float e00 = xi.x + x0.x, e01 = xi.y + x0.y;
        float e10 = xi.x + x1.x, e11 = xi.y + x1.y;
        e00 = fmaxf(e00, 0.2f * e00);
        e01 = fmaxf(e01, 0.2f * e01);
        e10 = fmaxf(e10, 0.2f * e10);
        e11 = fmaxf(e11, 0.2f * e11);
        float p0 = e00 * at.x + e01 * at.y;
        float p1 = e10 * at.x + e11 * at.y;
        p0 += __shfl_xor(p0, 1, 64);  p1 += __shfl_xor(p1, 1, 64);
        p0 += __shfl_xor(p0, 2, 64);  p1 += __shfl_xor(p1, 2, 64);
        p0 += __shfl_xor(p0, 4, 64);  p1 += __shfl_xor(p1, 4, 64);
        p0 += __shfl_xor(p0, 8, 64);  p1 += __shfl_xor(p1, 8, 64);
        p0 += __shfl_xor(p0, 16, 64); p1 += __shfl_xor(p1, 16, 64);
        float w0 = __expf(p0);
        float w1 = __expf(p1);
        den += w0 + w1;
        a0  += w0 * x0.x + w1 * x1.x;
        a1  += w0 * x0.y + w1 * x1.y;
    }
    if (k < end) {
        int s0 = srcs[k];
        float2 x0 = *(const float2*)&xl[(size_t)s0 * 128 + ch];
        float e00 = xi.x + x0.x, e01 = xi.y + x0.y;
        e00 = fmaxf(e00, 0.2f * e00);
        e01 = fmaxf(e01, 0.2f * e01);
        float p0 = e00 * at.x + e01 * at.y;
        p0 += __shfl_xor(p0, 1, 64);
        p0 += __shfl_xor(p0, 2, 64);
        p0 += __shfl_xor(p0, 4, 64);
        p0 += __shfl_xor(p0, 8, 64);
        p0 += __shfl_xor(p0, 16, 64);
        float w0 = __expf(p0);
        den += w0;
        a0  += w0 * x0.x;
        a1  += w0 * x0.y;
    }

    float inv = 1.0f / (den + 1e-16f);
    float r0 = a0 * inv;
    float r1 = a1 * inv;
    float q0 = __shfl_xor(r0, 32, 64);
    float q1 = __shfl_xor(r1, 32, 64);
    if (lane < 32) {
        float2 bv = *(const float2*)&bias[2 * j];
        float2 o = make_float2(0.5f * (r0 + q0) + bv.x,
                               0.5f * (r1 + q1) + bv.y);
        *(float2*)&out[(size_t)d * 64 + 2 * j] = o;
    }
}

extern "C" void kernel_launch(void* const* d_in, const int* in_sizes, int n_in,
                              void* d_out, int out_size, void* d_ws, size_t ws_size,
                              hipStream_t stream)
{
    const float* x_user   = (const float*)d_in[0];
    const float* x_item   = (const float*)d_in[1];
    const int*   src_u2i  = (const int*)d_in[2];
    const int*   dst_u2i  = (const int*)d_in[3];
    const int*   src_i2u  = (const int*)d_in[4];
    const int*   dst_i2u  = (const int*)d_in[5];
    const float* Wl_u2i   = (const float*)d_in[6];
    const float* bl_u2i   = (const float*)d_in[7];
    const float* Wr_u2i   = (const float*)d_in[8];
    const float* br_u2i   = (const float*)d_in[9];
    const float* att_u2i  = (const float*)d_in[10];
    const float* bias_u2i = (const float*)d_in[11];
    const float* Wl_i2u   = (const float*)d_in[12];
    const float* bl_i2u   = (const float*)d_in[13];
    const float* Wr_i2u   = (const float*)d_in[14];
    const float* br_i2u   = (const float*)d_in[15];
    const float* att_i2u  = (const float*)d_in[16];
    const float* bias_i2u = (const float*)d_in[17];

    const int n_user = in_sizes[0] / 128;
    const int n_item = in_sizes[1] / 128;
    const int E      = in_sizes[2];
    const int n_all  = n_item + n_user;      // rowptr: [0,n_item)=u2i, rest=i2u

    float* out_user = (float*)d_out;                   // [n_user,64]
    float* out_item = out_user + (size_t)n_user * 64;  // [n_item,64]

    char* w = (char*)d_ws;
    float* xl_u2i = (float*)w; w += (size_t)n_user * 128 * 4;
    float* xr_u2i = (float*)w; w += (size_t)n_item * 128 * 4;
    float* xl_i2u = (float*)w; w += (size_t)n_item * 128 * 4;
    float* xr_i2u = (float*)w; w += (size_t)n_user * 128 * 4;
    int* srcs_all   = (int*)w; w += (size_t)2 * E * 4;
    int* rowptr_all = (int*)w; w += (size_t)(n_all + 1) * 4;
    int* cnt_all    = (int*)w; w += (size_t)n_all * 4;     // reused as cursor
    int* bsum       = (int*)w; w += (size_t)SCAN_B * 4;
    unsigned short* WTuh = (unsigned short*)w; w += (size_t)256 * 128 * 2;
    unsigned short* WTul = (unsigned short*)w; w += (size_t)256 * 128 * 2;
    unsigned short* WTih = (unsigned short*)w; w += (size_t)256 * 128 * 2;
    unsigned short* WTil = (unsigned short*)w; w += (size_t)256 * 128 * 2;

    const int nb = (n_all + SCAN_B - 1) / SCAN_B;

    // ---- W prep (transpose + hi/lo split); independent of CSR ----
    k_wprep<<<512, 64, 0, stream>>>(Wl_u2i, Wr_i2u, Wl_i2u, Wr_u2i,
                                    WTuh, WTul, WTih, WTil);

    // ---- CSR build (both directions share one scan) ----
    k_zero<<<(n_all + 255) / 256, 256, 0, stream>>>(cnt_all, n_all);
    k_hist<<<(2 * E + 255) / 256, 256, 0, stream>>>(dst_u2i, dst_i2u, cnt_all, n_item, E);
    k_scan1<<<nb, SCAN_B, 0, stream>>>(cnt_all, n_all, rowptr_all, bsum);
    k_scan2<<<1, SCAN_B, 0, stream>>>(bsum, nb);
    k_scan3<<<(n_all + 255) / 256, 256, 0, stream>>>(rowptr_all, cnt_all, bsum, n_all, 2 * E);
    k_fill<<<(2 * E + 255) / 256, 256, 0, stream>>>(
        src_u2i, dst_u2i, src_i2u, dst_i2u, cnt_all, srcs_all, n_item, E);

    // ---- node linear transforms: split-bf16 MFMA, both node types ----
    const int nw0 = (n_user + 31) / 32;
    const int nw1 = (n_item + 31) / 32;
    const int nw_all = nw0 + nw1;
    gemm_mfma<<<(nw_all + 3) / 4, 256, 0, stream>>>(
        x_user, WTuh, WTul, bl_u2i, br_i2u, xl_u2i, xr_i2u, n_user, nw0,
        x_item, WTih, WTil, bl_i2u, br_u2i, xl_i2u, xr_u2i, n_item, nw_all);

    // ---- fused single-pass GAT, both directions in one launch ----
    k_gat2<<<(n_all + 3) / 4, 256, 0, stream>>>(
        xl_u2i, xr_u2i, att_u2i, bias_u2i, out_item,
        xl_i2u, xr_i2u, att_i2u, bias_i2u, out_user,
        rowptr_all, srcs_all, n_item, n_all);
}